// Round 2
// baseline (1349.411 us; speedup 1.0000x reference)
//
#include <hip/hip_runtime.h>
#include <hip/hip_bf16.h>
#include <cmath>

// Problem constants
#define Bq   4
#define Lq   4096
#define Wq   2048
#define Hq   8
#define Mq   (Bq*Lq)        // 16384 positions
#define CCH  64             // chunks per sequence (chunk = 64 rows = one block tile)

typedef __bf16 bf16;
typedef __attribute__((ext_vector_type(8))) __bf16 bf16x8;
typedef __attribute__((ext_vector_type(4))) float  f32x4;

// ---- workspace layout (bytes) ----
#define WS_WT    0                    // bf16 [2][8][256][256] = 2 MiB (n-major)
#define WS_C     (2*8*256*256*2)      // float [2048]
#define WS_AGG   (4u<<20)             // u64 [8192*64] = 4 MiB  (per-chunk aggregate (A,H) per col)
#define WS_INCL  (8u<<20)             // u64 [8192*64] = 4 MiB  (inclusive prefix (A,H) per col)
#define WS_FLAG  (12u<<20)            // u32 [8192]    flags: 0=none 1=agg 2=inclusive

union pack2 { unsigned long long u; float2 f; };

// ---------------- K0: weight transpose/cast (LDS tiled) + c vector ----------------
__global__ __launch_bounds__(256) void prep2(const float* __restrict__ ig_w,
                                             const float* __restrict__ ag_w,
                                             const float* __restrict__ a_param,
                                             bf16* __restrict__ wt, float* __restrict__ c_arr) {
    __shared__ float t[64*65];
    int bid = blockIdx.x;                 // 256 blocks: [g:1][h:3][nt:2][kt:2]
    int kt = bid & 3, nt = (bid >> 2) & 3, h = (bid >> 4) & 7, g = bid >> 7;
    const float* src = g ? ag_w : ig_w;
    int rr = threadIdx.x >> 6, cc = threadIdx.x & 63;
#pragma unroll
    for (int p = 0; p < 16; p++) {
        int kl = p*4 + rr;                // local k row
        t[kl*65 + cc] = src[h*65536 + (kt*64 + kl)*256 + nt*64 + cc];  // coalesced read
    }
    if (bid < 8) {
        float ap = a_param[bid*256 + threadIdx.x];
        c_arr[bid*256 + threadIdx.x] = 8.0f * log1pf(__expf(ap));      // 8*softplus
    }
    __syncthreads();
#pragma unroll
    for (int p = 0; p < 16; p++) {
        int nl = p*4 + rr;                // local n row
        wt[((size_t)((g*8 + h)*256) + nt*64 + nl)*256 + kt*64 + cc] = (bf16)t[cc*65 + nl]; // coalesced write
    }
}

// ---------------- K1: fully fused RG-LRU (GEMM + gates + scan + lookback) ----------------
// 1-D grid 8192: gid = by*256 + bx ; bx = b*64 + chunk (chain order == dispatch order),
// by = head*4 + ntile. Block = 256 thr = 4 waves, 2x2 wave grid over a 64x64 tile.
__global__ __launch_bounds__(256) void rglru_fused(
    const float* __restrict__ x, const int* __restrict__ segpos,
    const float* __restrict__ prev_h,
    const bf16* __restrict__ wt, const float* __restrict__ igb,
    const float* __restrict__ agb, const float* __restrict__ c_arr,
    unsigned long long* __restrict__ agg, unsigned long long* __restrict__ incl,
    unsigned int* __restrict__ flg, float* __restrict__ out)
{
    union SharedU {
        struct { bf16 As[64*72]; bf16 Wxs[64*72]; bf16 Was[64*72]; } st;   // GEMM staging
        struct { float A_s[64*65]; float G_s[64*65]; } ep;                 // epilogue (a, gx*mult)
    };
    __shared__ SharedU sh;
    __shared__ float segA[4*64], segH[4*64], carryL[64];
    __shared__ unsigned char rs[64];

    const int tid = threadIdx.x;
    const int gid = blockIdx.x;
    const int bx  = gid & 255, by = gid >> 8;
    const int b   = bx >> 6,   c  = bx & 63;      // batch, chunk
    const int m0  = bx * 64;
    const int h   = by >> 2,   nt = by & 3;
    const int n0  = nt * 64;
    const int wofs = h*256 + n0;

    const int lane = tid & 63, wid = tid >> 6;
    const int wm = wid >> 1, wn = wid & 1;
    const int l16 = lane & 15, quad = lane >> 4;

    if (tid < 64) rs[tid] = (segpos[(m0 + tid) & (Lq-1)] == 0) ? 1 : 0;

    f32x4 accx[2][2], acca[2][2];
#pragma unroll
    for (int i = 0; i < 2; i++)
#pragma unroll
        for (int j = 0; j < 2; j++) {
            accx[i][j] = (f32x4){0.f,0.f,0.f,0.f};
            acca[i][j] = (f32x4){0.f,0.f,0.f,0.f};
        }

    const bf16* wtx = wt + ((size_t)((0*Hq + h)*256 + n0))*256;
    const bf16* wta = wt + ((size_t)((1*Hq + h)*256 + n0))*256;

    for (int kk = 0; kk < 256; kk += 64) {
        __syncthreads();
#pragma unroll
        for (int p = 0; p < 2; p++) {
            int lin = p*2048 + tid*8;
            int r = lin >> 6, cc = lin & 63;
            const float* gp = x + (size_t)(m0 + r)*Wq + h*256 + kk + cc;
            float4 f0 = *(const float4*)gp;
            float4 f1 = *(const float4*)(gp + 4);
            bf16x8 v;
            v[0]=(bf16)f0.x; v[1]=(bf16)f0.y; v[2]=(bf16)f0.z; v[3]=(bf16)f0.w;
            v[4]=(bf16)f1.x; v[5]=(bf16)f1.y; v[6]=(bf16)f1.z; v[7]=(bf16)f1.w;
            *(bf16x8*)&sh.st.As[r*72 + cc] = v;
        }
#pragma unroll
        for (int p = 0; p < 2; p++) {
            int lin = p*2048 + tid*8;
            int r = lin >> 6, cc = lin & 63;
            *(bf16x8*)&sh.st.Wxs[r*72 + cc] = *(const bf16x8*)&wtx[(size_t)r*256 + kk + cc];
            *(bf16x8*)&sh.st.Was[r*72 + cc] = *(const bf16x8*)&wta[(size_t)r*256 + kk + cc];
        }
        __syncthreads();
#pragma unroll
        for (int ks = 0; ks < 2; ks++) {
            bf16x8 af[2], bxf[2], baf[2];
#pragma unroll
            for (int i = 0; i < 2; i++) {
                af[i]  = *(bf16x8*)&sh.st.As [(wm*32 + i*16 + l16)*72 + ks*32 + quad*8];
                bxf[i] = *(bf16x8*)&sh.st.Wxs[(wn*32 + i*16 + l16)*72 + ks*32 + quad*8];
                baf[i] = *(bf16x8*)&sh.st.Was[(wn*32 + i*16 + l16)*72 + ks*32 + quad*8];
            }
#pragma unroll
            for (int i = 0; i < 2; i++)
#pragma unroll
                for (int j = 0; j < 2; j++) {
                    accx[i][j] = __builtin_amdgcn_mfma_f32_16x16x32_bf16(af[i], bxf[j], accx[i][j], 0, 0, 0);
                    acca[i][j] = __builtin_amdgcn_mfma_f32_16x16x32_bf16(af[i], baf[j], acca[i][j], 0, 0, 0);
                }
        }
    }
    __syncthreads();   // staging dead; union reuse below

    // ---- pass 1: gates -> (a, gx*mult) into LDS [row][col] (fast-math) ----
#pragma unroll
    for (int i = 0; i < 2; i++)
#pragma unroll
        for (int j = 0; j < 2; j++) {
            int col = wn*32 + j*16 + l16;
            int wf  = wofs + col;
            float bxv = igb[wf], bav = agb[wf], cc2 = c_arr[wf];
#pragma unroll
            for (int r = 0; r < 4; r++) {
                int row = wm*32 + i*16 + quad*4 + r;
                float zx = accx[i][j][r] + bxv;
                float za = acca[i][j][r] + bav;
                float gx = __builtin_amdgcn_rcpf(1.f + __expf(-zx));
                float ga = __builtin_amdgcn_rcpf(1.f + __expf(-za));
                float la = -ga * cc2;
                float a  = __expf(la);
                float mult = __builtin_amdgcn_sqrtf(fmaf(-a, a, 1.f)); // sqrt(1-a^2)
                if (rs[row]) { a = 0.f; mult = 1.f; }
                sh.ep.A_s[row*65 + col] = a;
                sh.ep.G_s[row*65 + col] = gx * mult;
            }
        }
    __syncthreads();

    // ---- pass 2: per-column segmented scan (4 segs x 16 rows) ----
    const int col2 = tid & 63, seg = tid >> 6;
    float Pl[16], hl[16];
    {
        float A = 1.f, hv = 0.f;
        const float* xp = x + (size_t)(m0 + seg*16)*Wq + wofs + col2;
#pragma unroll
        for (int r = 0; r < 16; r++) {
            int row = seg*16 + r;
            float a  = sh.ep.A_s[row*65 + col2];
            float xn = sh.ep.G_s[row*65 + col2] * xp[(size_t)r*Wq];
            hv = fmaf(a, hv, xn);
            A *= a;
            Pl[r] = A; hl[r] = hv;
        }
        segA[seg*64 + col2] = A;
        segH[seg*64 + col2] = hv;
    }
    __syncthreads();
    float Ap = 1.f, Hp = 0.f;                       // prefix over segs < seg
#pragma unroll
    for (int s = 0; s < 3; s++)
        if (s < seg) {
            Hp = fmaf(segA[s*64 + col2], Hp, segH[s*64 + col2]);
            Ap *= segA[s*64 + col2];
        }

    // ---- pass 3: decoupled lookback (wave 3 only; per-column payloads) ----
    if (seg == 3) {
        float Ach = Ap * Pl[15];                    // chunk aggregate A
        float Hch = fmaf(Pl[15], Hp, hl[15]);       // chunk aggregate H
        int  sidx = gid*64 + col2;
        float carry;
        if (c == 0) {
            carry = prev_h[b*Wq + wofs + col2];
        } else {
            pack2 pv; pv.f.x = Ach; pv.f.y = Hch;
            __hip_atomic_store(&agg[sidx], pv.u, __ATOMIC_RELAXED, __HIP_MEMORY_SCOPE_AGENT);
            if (col2 == 0)
                __hip_atomic_store(&flg[gid], 1u, __ATOMIC_RELEASE, __HIP_MEMORY_SCOPE_AGENT);
            float Ar = 1.f, Hr = 0.f;               // h_end(gid-1) = Hr + Ar*h_end(p)
            int p = gid - 1;
            for (;;) {
                unsigned f;
                while ((f = __hip_atomic_load(&flg[p], __ATOMIC_ACQUIRE, __HIP_MEMORY_SCOPE_AGENT)) == 0u)
                    __builtin_amdgcn_s_sleep(1);
                pack2 q;
                if (f == 2u) {
                    q.u = __hip_atomic_load(&incl[p*64 + col2], __ATOMIC_RELAXED, __HIP_MEMORY_SCOPE_AGENT);
                    carry = fmaf(Ar, q.f.y, Hr);
                    break;
                } else {
                    q.u = __hip_atomic_load(&agg[p*64 + col2], __ATOMIC_RELAXED, __HIP_MEMORY_SCOPE_AGENT);
                    Hr = fmaf(Ar, q.f.y, Hr);
                    Ar *= q.f.x;
                    p--;
                }
            }
        }
        float Hinc = fmaf(Ach, carry, Hch);         // inclusive h at chunk end
        pack2 iv; iv.f.x = Ach; iv.f.y = Hinc;
        __hip_atomic_store(&incl[sidx], iv.u, __ATOMIC_RELAXED, __HIP_MEMORY_SCOPE_AGENT);
        if (col2 == 0)
            __hip_atomic_store(&flg[gid], 2u, __ATOMIC_RELEASE, __HIP_MEMORY_SCOPE_AGENT);
        if (c == CCH-1)
            out[(size_t)Mq*Wq + b*Wq + wofs + col2] = Hinc;   // last_h
        carryL[col2] = carry;
    }
    __syncthreads();

    // ---- pass 4: apply carry, write y coalesced ----
    float hin = fmaf(Ap, carryL[col2], Hp);         // h entering my segment
    float* yp = out + (size_t)(m0 + seg*16)*Wq + wofs + col2;
#pragma unroll
    for (int r = 0; r < 16; r++)
        yp[(size_t)r*Wq] = fmaf(Pl[r], hin, hl[r]);
}

extern "C" void kernel_launch(void* const* d_in, const int* in_sizes, int n_in,
                              void* d_out, int out_size, void* d_ws, size_t ws_size,
                              hipStream_t stream) {
    const float* x       = (const float*)d_in[0];
    const int*   segpos  = (const int*)  d_in[1];
    const float* prev_h  = (const float*)d_in[2];
    const float* ig_w    = (const float*)d_in[3];
    const float* ig_b    = (const float*)d_in[4];
    const float* ag_w    = (const float*)d_in[5];
    const float* ag_b    = (const float*)d_in[6];
    const float* a_param = (const float*)d_in[7];
    float* out = (float*)d_out;                    // [M*W] y then [B*W] last_h

    char* ws = (char*)d_ws;
    bf16*  wt    = (bf16*) (ws + WS_WT);
    float* c_arr = (float*)(ws + WS_C);
    unsigned long long* agg  = (unsigned long long*)(ws + WS_AGG);
    unsigned long long* incl = (unsigned long long*)(ws + WS_INCL);
    unsigned int*       flg  = (unsigned int*)      (ws + WS_FLAG);

    hipMemsetAsync(flg, 0, 8192*sizeof(unsigned int), stream);
    prep2<<<256, 256, 0, stream>>>(ig_w, ag_w, a_param, wt, c_arr);
    rglru_fused<<<8192, 256, 0, stream>>>(x, segpos, prev_h, wt, ig_b, ag_b, c_arr,
                                          agg, incl, flg, out);
}

// Round 4
// 442.022 us; speedup vs baseline: 3.0528x; 3.0528x over previous
//
#include <hip/hip_runtime.h>
#include <hip/hip_bf16.h>
#include <cmath>

// Problem constants
#define Bq   4
#define Lq   4096
#define Wq   2048
#define Hq   8
#define Mq   (Bq*Lq)        // 16384 rows
#define TCH  64             // rows per chunk (= block tile M)
#define CCH  (Lq/TCH)       // 64 chunks per sequence

typedef __bf16 bf16;
typedef __attribute__((ext_vector_type(8))) __bf16 bf16x8;
typedef __attribute__((ext_vector_type(4))) float  f32x4;

// ---- workspace layout (bytes) ----
#define WS_WT    0                               // bf16 [2][8][256][256] = 2 MiB (n-major)
#define WS_C     (2*8*256*256*2)                 // float [2048]
#define WS_PH    (4u<<20)                        // uint [Mq*Wq]: packed (bf16 P, bf16 H) = 134 MiB
#define WS_AGG   (WS_PH + (size_t)Mq*Wq*4)       // float2 [B][CCH][W] = 4 MiB (fp32: exact carries)
#define WS_CARRY (WS_AGG + (size_t)Bq*CCH*Wq*8)  // float [B][CCH][W] = 2 MiB

union pkPH { unsigned u; bf16 v[2]; };

// ---------------- K0: weight transpose/cast (LDS tiled) + c vector ----------------
__global__ __launch_bounds__(256) void prep2(const float* __restrict__ ig_w,
                                             const float* __restrict__ ag_w,
                                             const float* __restrict__ a_param,
                                             bf16* __restrict__ wt, float* __restrict__ c_arr) {
    __shared__ float t[64*65];
    int bid = blockIdx.x;                 // 256 blocks: [g:1][h:3][nt:2][kt:2]
    int kt = bid & 3, nt = (bid >> 2) & 3, h = (bid >> 4) & 7, g = bid >> 7;
    const float* src = g ? ag_w : ig_w;
    int rr = threadIdx.x >> 6, cc = threadIdx.x & 63;
#pragma unroll
    for (int p = 0; p < 16; p++) {
        int kl = p*4 + rr;
        t[kl*65 + cc] = src[h*65536 + (kt*64 + kl)*256 + nt*64 + cc];  // coalesced read
    }
    if (bid < 8) {
        float ap = a_param[bid*256 + threadIdx.x];
        c_arr[bid*256 + threadIdx.x] = 8.0f * log1pf(__expf(ap));      // 8*softplus
    }
    __syncthreads();
#pragma unroll
    for (int p = 0; p < 16; p++) {
        int nl = p*4 + rr;
        wt[((size_t)((g*8 + h)*256) + nt*64 + nl)*256 + kt*64 + cc] = (bf16)t[cc*65 + nl]; // coalesced write
    }
}

// ---------------- K1: GEMM + gates + chunk-local scan -> packed (P,H) + fp32 aggs ----
// grid (256, 32): blockIdx.x = m-tile (b*64+c), blockIdx.y = h*4 + nt.
// Block = 256 thr = 4 waves, 2x2 wave grid over a 64x64 output tile.
__global__ __launch_bounds__(256) void gates_scan(
    const float* __restrict__ x, const int* __restrict__ segpos,
    const bf16* __restrict__ wt, const float* __restrict__ igb,
    const float* __restrict__ agb, const float* __restrict__ c_arr,
    unsigned* __restrict__ PH, float2* __restrict__ agg)
{
    union SharedU {
        struct { bf16 As[64*72]; bf16 Wxs[64*72]; bf16 Was[64*72]; } st;   // GEMM staging
        struct { float A_s[64*65]; float G_s[64*65]; } ep;                 // epilogue (a, gx*mult)
    };
    __shared__ SharedU sh;
    __shared__ float segA[4*64], segH[4*64];
    __shared__ unsigned char rs[64];

    const int tid = threadIdx.x;
    const int bx  = blockIdx.x, by = blockIdx.y;
    const int b   = bx >> 6,    c  = bx & 63;      // batch, chunk
    const int m0  = bx * 64;
    const int h   = by >> 2,    nt = by & 3;
    const int n0  = nt * 64;
    const int wofs = h*256 + n0;

    const int lane = tid & 63, wid = tid >> 6;
    const int wm = wid >> 1, wn = wid & 1;
    const int l16 = lane & 15, quad = lane >> 4;

    if (tid < 64) rs[tid] = (segpos[(m0 + tid) & (Lq-1)] == 0) ? 1 : 0;

    f32x4 accx[2][2], acca[2][2];
#pragma unroll
    for (int i = 0; i < 2; i++)
#pragma unroll
        for (int j = 0; j < 2; j++) {
            accx[i][j] = (f32x4){0.f,0.f,0.f,0.f};
            acca[i][j] = (f32x4){0.f,0.f,0.f,0.f};
        }

    const bf16* wtx = wt + ((size_t)((0*Hq + h)*256 + n0))*256;
    const bf16* wta = wt + ((size_t)((1*Hq + h)*256 + n0))*256;

    for (int kk = 0; kk < 256; kk += 64) {
        __syncthreads();
#pragma unroll
        for (int p = 0; p < 2; p++) {
            int lin = p*2048 + tid*8;
            int r = lin >> 6, cc = lin & 63;
            const float* gp = x + (size_t)(m0 + r)*Wq + h*256 + kk + cc;
            float4 f0 = *(const float4*)gp;
            float4 f1 = *(const float4*)(gp + 4);
            bf16x8 v;
            v[0]=(bf16)f0.x; v[1]=(bf16)f0.y; v[2]=(bf16)f0.z; v[3]=(bf16)f0.w;
            v[4]=(bf16)f1.x; v[5]=(bf16)f1.y; v[6]=(bf16)f1.z; v[7]=(bf16)f1.w;
            *(bf16x8*)&sh.st.As[r*72 + cc] = v;
        }
#pragma unroll
        for (int p = 0; p < 2; p++) {
            int lin = p*2048 + tid*8;
            int r = lin >> 6, cc = lin & 63;
            *(bf16x8*)&sh.st.Wxs[r*72 + cc] = *(const bf16x8*)&wtx[(size_t)r*256 + kk + cc];
            *(bf16x8*)&sh.st.Was[r*72 + cc] = *(const bf16x8*)&wta[(size_t)r*256 + kk + cc];
        }
        __syncthreads();
#pragma unroll
        for (int ks = 0; ks < 2; ks++) {
            bf16x8 af[2], bxf[2], baf[2];
#pragma unroll
            for (int i = 0; i < 2; i++) {
                af[i]  = *(bf16x8*)&sh.st.As [(wm*32 + i*16 + l16)*72 + ks*32 + quad*8];
                bxf[i] = *(bf16x8*)&sh.st.Wxs[(wn*32 + i*16 + l16)*72 + ks*32 + quad*8];
                baf[i] = *(bf16x8*)&sh.st.Was[(wn*32 + i*16 + l16)*72 + ks*32 + quad*8];
            }
#pragma unroll
            for (int i = 0; i < 2; i++)
#pragma unroll
                for (int j = 0; j < 2; j++) {
                    accx[i][j] = __builtin_amdgcn_mfma_f32_16x16x32_bf16(af[i], bxf[j], accx[i][j], 0, 0, 0);
                    acca[i][j] = __builtin_amdgcn_mfma_f32_16x16x32_bf16(af[i], baf[j], acca[i][j], 0, 0, 0);
                }
        }
    }
    __syncthreads();   // staging dead; union reuse below

    // ---- pass 1: gates -> (a, gx*mult) into LDS [row][col] (fast-math) ----
#pragma unroll
    for (int i = 0; i < 2; i++)
#pragma unroll
        for (int j = 0; j < 2; j++) {
            int col = wn*32 + j*16 + l16;
            int wf  = wofs + col;
            float bxv = igb[wf], bav = agb[wf], cc2 = c_arr[wf];
#pragma unroll
            for (int r = 0; r < 4; r++) {
                int row = wm*32 + i*16 + quad*4 + r;
                float zx = accx[i][j][r] + bxv;
                float za = acca[i][j][r] + bav;
                float gx = __builtin_amdgcn_rcpf(1.f + __expf(-zx));
                float ga = __builtin_amdgcn_rcpf(1.f + __expf(-za));
                float la = -ga * cc2;
                float a  = __expf(la);
                float mult = __builtin_amdgcn_sqrtf(fmaf(-a, a, 1.f)); // sqrt(1-a^2)
                if (rs[row]) { a = 0.f; mult = 1.f; }
                sh.ep.A_s[row*65 + col] = a;
                sh.ep.G_s[row*65 + col] = gx * mult;
            }
        }
    __syncthreads();

    // ---- pass 2: per-column segmented scan (4 segs x 16 rows) ----
    const int col2 = tid & 63, seg = tid >> 6;
    float Pl[16], hl[16];
    {
        float A = 1.f, hv = 0.f;
        const float* xp = x + (size_t)(m0 + seg*16)*Wq + wofs + col2;
#pragma unroll
        for (int r = 0; r < 16; r++) {
            int row = seg*16 + r;
            float a  = sh.ep.A_s[row*65 + col2];
            float xn = sh.ep.G_s[row*65 + col2] * xp[(size_t)r*Wq];   // x re-read: L2-hot
            hv = fmaf(a, hv, xn);
            A *= a;
            Pl[r] = A; hl[r] = hv;
        }
        segA[seg*64 + col2] = A;
        segH[seg*64 + col2] = hv;
    }
    __syncthreads();
    float Ap = 1.f, Hp = 0.f;                       // prefix over segs < seg (in-block, exact)
#pragma unroll
    for (int s = 0; s < 3; s++)
        if (s < seg) {
            Hp = fmaf(segA[s*64 + col2], Hp, segH[s*64 + col2]);
            Ap *= segA[s*64 + col2];
        }

    // ---- store packed chunk-relative (P, H), bf16 each (single rounding) ----
    unsigned* php = PH + (size_t)(m0 + seg*16)*Wq + wofs + col2;
#pragma unroll
    for (int r = 0; r < 16; r++) {
        float Pf = Ap * Pl[r];
        float Hf = fmaf(Pl[r], Hp, hl[r]);
        pkPH pk; pk.v[0] = (bf16)Pf; pk.v[1] = (bf16)Hf;
        php[(size_t)r*Wq] = pk.u;                   // 64 lanes * 4B contiguous
    }

    // ---- chunk aggregate (fp32, exact) for the chain scan ----
    if (seg == 3) {
        float Ach = Ap * Pl[15];
        float Hch = fmaf(Pl[15], Hp, hl[15]);
        agg[(size_t)(b*CCH + c)*Wq + wofs + col2] = make_float2(Ach, Hch);
    }
}

// ---------------- K2: serial scan over chunk chain (fp32 exact) ----------------
__global__ __launch_bounds__(256) void chain_scan(
    const float2* __restrict__ agg, const float* __restrict__ prev_h,
    float* __restrict__ carry, float* __restrict__ last_h)
{
    int tid = blockIdx.x*256 + threadIdx.x;   // B*W = 8192 chains
    int w = tid & (Wq - 1), b = tid >> 11;
    float h = prev_h[tid];
    for (int c = 0; c < CCH; c++) {
        int idx = (b*CCH + c)*Wq + w;
        carry[idx] = h;
        float2 ah = agg[idx];
        h = fmaf(ah.x, h, ah.y);
    }
    last_h[tid] = h;
}

// ---------------- K3: elementwise apply y = P*carry + H ----------------
__global__ __launch_bounds__(256) void apply_carry(
    const unsigned* __restrict__ PH, const float* __restrict__ carry,
    float* __restrict__ y)
{
    size_t i4 = ((size_t)blockIdx.x*256 + threadIdx.x) * 4;   // 4 elems/thread
    uint4 p = *(const uint4*)(PH + i4);
    int w = (int)(i4 & (Wq - 1));
    int m = (int)(i4 >> 11);
    int b = m >> 12;                 // / Lq
    int c = (m & (Lq - 1)) >> 6;     // / TCH
    // BUGFIX (round 3): carry varies per channel w — load all 4, not one scalar
    float4 cr4 = *(const float4*)(carry + (size_t)(b*CCH + c)*Wq + w);
    float4 o;
    pkPH k;
    k.u = p.x; o.x = fmaf((float)k.v[0], cr4.x, (float)k.v[1]);
    k.u = p.y; o.y = fmaf((float)k.v[0], cr4.y, (float)k.v[1]);
    k.u = p.z; o.z = fmaf((float)k.v[0], cr4.z, (float)k.v[1]);
    k.u = p.w; o.w = fmaf((float)k.v[0], cr4.w, (float)k.v[1]);
    *(float4*)(y + i4) = o;
}

extern "C" void kernel_launch(void* const* d_in, const int* in_sizes, int n_in,
                              void* d_out, int out_size, void* d_ws, size_t ws_size,
                              hipStream_t stream) {
    const float* x       = (const float*)d_in[0];
    const int*   segpos  = (const int*)  d_in[1];
    const float* prev_h  = (const float*)d_in[2];
    const float* ig_w    = (const float*)d_in[3];
    const float* ig_b    = (const float*)d_in[4];
    const float* ag_w    = (const float*)d_in[5];
    const float* ag_b    = (const float*)d_in[6];
    const float* a_param = (const float*)d_in[7];
    float* out = (float*)d_out;                    // [M*W] y then [B*W] last_h

    char* ws = (char*)d_ws;
    bf16*   wt    = (bf16*)  (ws + WS_WT);
    float*  c_arr = (float*) (ws + WS_C);
    unsigned* PH  = (unsigned*)(ws + WS_PH);
    float2* agg   = (float2*)(ws + WS_AGG);
    float*  carry = (float*) (ws + WS_CARRY);

    prep2<<<256, 256, 0, stream>>>(ig_w, ag_w, a_param, wt, c_arr);

    dim3 g1(Mq/64, Hq*4);
    gates_scan<<<g1, 256, 0, stream>>>(x, segpos, wt, ig_b, ag_b, c_arr, PH, agg);

    chain_scan<<<(Bq*Wq)/256, 256, 0, stream>>>(agg, prev_h, carry, out + (size_t)Mq*Wq);

    apply_carry<<<(int)(((size_t)Mq*Wq/4)/256), 256, 0, stream>>>(PH, carry, out);
}